// Round 10
// baseline (581.142 us; speedup 1.0000x reference)
//
#include <hip/hip_runtime.h>
#include <hip/hip_fp16.h>
#include <stdint.h>

// MPNN layer (R10 = R9 + compile fix): algebraic restructure.
//  h[e] = P1[src] + P2[dst] + ea@W1c + b1 ; u = silu(LN(h))
//  agg[d] = (sum_{e->d} u[e]) @ W2 + deg(d)*b2   (MFMA distributes over sum)
// Pipeline:
//  1. hist+packs (prep), counting-sort edges by dst (cursor/cnt give ranges)
//  2. P12 = x @ [W1a|W1b] dense GEMM (N,256) bf16
//  3. edge kernel: wave owns 2 nodes; per edge: gather P1 pair (u32), uniform
//     ea row read, 32 v_dot2_f32_f16 for the ea-term, wave-wide LN, silu,
//     accumulate u in registers -> PLAIN stores to S (no atomics/LDS/barriers)
//  4. T = S @ W2 dense GEMM (N,128) f32 (aliases P12 storage)
//  5. upd: stage [x, T + cnt*b2] -> MLP + residual (proven R5-R8 structure)

#define N_NODES 100000
#define N_EDGES 800000
#define NODE_DIM 64
#define EDGE_DIM 32
#define HIDDEN 128
#define LN_EPS 1e-5f

#define PH 136   // bf16 tile pitch, 128 data cols
#define PX 72    // P12-GEMM A pitch (64 data cols)
#define PU 200   // upd A-tile pitch (192 data cols)

#define NB_SCAN ((N_NODES + 1023) / 1024)   // 98

typedef __attribute__((ext_vector_type(8))) short short8;
typedef __attribute__((ext_vector_type(4))) float f32x4;
typedef __attribute__((ext_vector_type(2))) _Float16 h2;

static __device__ __forceinline__ uint16_t f2bf(float f) {
  uint32_t u = __float_as_uint(f);
  return (uint16_t)((u + 0x7FFFu + ((u >> 16) & 1u)) >> 16);
}
static __device__ __forceinline__ float bf2f(uint16_t u) {
  return __uint_as_float(((uint32_t)u) << 16);
}

// ---------------- prepass: hist + pack all weights ----------------

#define PREP_HIST_BLKS 3125
#define PREP_PACK_BLKS 264   // 67584 elems

__global__ void prep_kernel(const int* __restrict__ ei, int* __restrict__ cnt,
                            const float* __restrict__ W1, uint16_t* __restrict__ Wcatp,
                            uint32_t* __restrict__ W1cpk,
                            const float* __restrict__ W2, uint16_t* __restrict__ W2p,
                            const float* __restrict__ Wu1, uint16_t* __restrict__ Wu1p,
                            const float* __restrict__ Wu2, uint16_t* __restrict__ Wu2p) {
  int b = blockIdx.x;
  if (b < PREP_HIST_BLKS) {
    int e = b * 256 + threadIdx.x;
    if (e < N_EDGES) atomicAdd(&cnt[ei[N_EDGES + e]], 1);
    return;
  }
  int i = (b - PREP_HIST_BLKS) * 256 + threadIdx.x;
  if (i < 16384) {          // Wcat: K=64, C=256  ([W1a | W1b])
    int k = i >> 8, c = i & 255;
    float v = (c < 128) ? W1[k * 128 + c] : W1[(64 + k) * 128 + (c - 128)];
    Wcatp[(((k >> 5) * 256 + c) * 4 + ((k >> 3) & 3)) * 8 + (k & 7)] = f2bf(v);
  } else if (i < 32768) {   // W2: K=128, C=128
    i -= 16384;
    int k = i >> 7, c = i & 127;
    W2p[(((k >> 5) * 128 + c) * 4 + ((k >> 3) & 3)) * 8 + (k & 7)] = f2bf(W2[i]);
  } else if (i < 57344) {   // Wu1: K=192, C=128
    i -= 32768;
    int k = i >> 7, c = i & 127;
    Wu1p[(((k >> 5) * 128 + c) * 4 + ((k >> 3) & 3)) * 8 + (k & 7)] = f2bf(Wu1[i]);
  } else if (i < 65536) {   // Wu2: K=128, C=64
    i -= 57344;
    int k = i >> 6, c = i & 63;
    Wu2p[(((k >> 5) * 64 + c) * 4 + ((k >> 3) & 3)) * 8 + (k & 7)] = f2bf(Wu2[i]);
  } else if (i < 67584) {   // W1c (rows 128..159 of W1) as f16 k-pairs
    int j = (i - 65536) >> 7, c = (i - 65536) & 127;
    float lo = W1[(128 + 2 * j) * 128 + c];
    float hi = W1[(129 + 2 * j) * 128 + c];
    uint32_t u = (uint32_t)__half_as_ushort(__float2half(lo))
               | ((uint32_t)__half_as_ushort(__float2half(hi)) << 16);
    W1cpk[j * 128 + c] = u;
  }
}

// ---------------- counting sort by dst ----------------

__global__ __launch_bounds__(256) void scan_blk(const int* __restrict__ cnt,
                                                int* __restrict__ offs,
                                                int* __restrict__ bsum) {
  __shared__ int wsum[4];
  int tid = threadIdx.x;
  int base = blockIdx.x * 1024 + tid * 4;
  int v0 = 0, v1 = 0, v2 = 0, v3 = 0;
  if (base < N_NODES) v0 = cnt[base];
  if (base + 1 < N_NODES) v1 = cnt[base + 1];
  if (base + 2 < N_NODES) v2 = cnt[base + 2];
  if (base + 3 < N_NODES) v3 = cnt[base + 3];
  int tsum = v0 + v1 + v2 + v3;
  int lane = tid & 63, wid = tid >> 6;
  int s = tsum;
  #pragma unroll
  for (int d = 1; d < 64; d <<= 1) {
    int t = __shfl_up(s, d);
    if (lane >= d) s += t;
  }
  if (lane == 63) wsum[wid] = s;
  __syncthreads();
  int woff = 0;
  for (int w = 0; w < wid; ++w) woff += wsum[w];
  int excl = woff + s - tsum;
  if (base < N_NODES) {
    int run = excl;
    offs[base] = run; run += v0;
    if (base + 1 < N_NODES) { offs[base + 1] = run; run += v1; }
    if (base + 2 < N_NODES) { offs[base + 2] = run; run += v2; }
    if (base + 3 < N_NODES) { offs[base + 3] = run; run += v3; }
  }
  if (tid == 255) bsum[blockIdx.x] = woff + s;
}

__global__ void scan_top(int* __restrict__ bsum) {
  __shared__ int sh[128];
  int tid = threadIdx.x;
  int v = (tid < NB_SCAN) ? bsum[tid] : 0;
  int orig = v;
  sh[tid] = v;
  __syncthreads();
  for (int d = 1; d < 128; d <<= 1) {
    int t = (tid >= d) ? sh[tid - d] : 0;
    __syncthreads();
    v += t;
    sh[tid] = v;
    __syncthreads();
  }
  if (tid < NB_SCAN) bsum[tid] = v - orig;
}

__global__ void scan_add(const int* __restrict__ offs, const int* __restrict__ bsum,
                         int* __restrict__ cursor) {
  int i = blockIdx.x * 256 + threadIdx.x;
  if (i < N_NODES) cursor[i] = offs[i] + bsum[i >> 10];
}

__global__ void scatter_edges(const int* __restrict__ ei, int* __restrict__ cursor,
                              int* __restrict__ src_s, int* __restrict__ eid_s) {
  int e = blockIdx.x * 256 + threadIdx.x;
  if (e < N_EDGES) {
    int s = ei[e], d = ei[N_EDGES + e];
    int p = atomicAdd(&cursor[d], 1);
    src_s[p] = s; eid_s[p] = e;
  }
}

// ---------------- P12 = x @ [W1a|W1b]  (N x 256, bf16) ----------------

__global__ __launch_bounds__(256) void p12_kernel(
    const float* __restrict__ x, const uint16_t* __restrict__ Wcatp,
    uint16_t* __restrict__ P12) {
  __shared__ __align__(16) uint16_t A[64 * PX];
  const int tid = threadIdx.x;
  const int n0 = blockIdx.x * 64;

  // stage x (f32 -> bf16): 64 rows x 64 cols
  #pragma unroll
  for (int it = 0; it < 4; ++it) {
    int u = tid + it * 256;
    int r = u >> 4, q = u & 15;
    int node = min(n0 + r, N_NODES - 1);
    float4 f = *(const float4*)(x + (size_t)node * 64 + q * 4);
    ushort4 o;
    o.x = f2bf(f.x); o.y = f2bf(f.y); o.z = f2bf(f.z); o.w = f2bf(f.w);
    *(ushort4*)(&A[r * PX + q * 4]) = o;
  }
  __syncthreads();

  const int wid = tid >> 6, lane = tid & 63;
  const int lrow = lane & 15, lk = lane >> 4;
  const int r0 = wid * 16;

  f32x4 acc[16] = {};
  const uint16_t* Abase = &A[(r0 + lrow) * PX + lk * 8];
  #pragma unroll
  for (int c = 0; c < 2; ++c) {
    short8 a = *(const short8*)(Abase + c * 32);
    #pragma unroll
    for (int n = 0; n < 16; ++n) {
      short8 b = *(const short8*)(Wcatp + ((size_t)(c * 256 + n * 16 + lrow) * 4 + lk) * 8);
      acc[n] = __builtin_amdgcn_mfma_f32_16x16x32_bf16(a, b, acc[n], 0, 0, 0);
    }
  }

  #pragma unroll
  for (int reg = 0; reg < 4; ++reg) {
    int row = n0 + r0 + lk * 4 + reg;
    if (row < N_NODES) {
      #pragma unroll
      for (int n = 0; n < 16; ++n) {
        P12[(size_t)row * 256 + n * 16 + lrow] = f2bf(acc[n][reg]);
      }
    }
  }
}

// ---------------- edge kernel: u = silu(LN(h)); S[d] = sum u ----------------
// No LDS, no barriers, no atomics. Wave owns 2 nodes; lane owns cols 2l,2l+1.

__global__ __launch_bounds__(256) void edge_kernel(
    const int* __restrict__ src_s, const int* __restrict__ eid_s,
    const int* __restrict__ cursor, const int* __restrict__ cnt,
    const float* __restrict__ ea, const uint16_t* __restrict__ P12,
    const uint32_t* __restrict__ W1cpk, const float* __restrict__ b1,
    const float* __restrict__ g1, const float* __restrict__ be1,
    float* __restrict__ S) {
  const int tid = threadIdx.x;
  const int wid = tid >> 6, lane = tid & 63;
  const int c0 = 2 * lane;

  // per-lane constants (L2-hot)
  uint2 w[16];
  #pragma unroll
  for (int j = 0; j < 16; ++j)
    w[j] = *(const uint2*)(W1cpk + j * 128 + c0);
  float2 b1v = *(const float2*)(b1 + c0);
  float2 gv  = *(const float2*)(g1 + c0);
  float2 bev = *(const float2*)(be1 + c0);

  const int gw = blockIdx.x * 4 + wid;   // 12500*4 waves * 2 nodes = 100000

  #pragma unroll
  for (int t = 0; t < 2; ++t) {
    int d = gw * 2 + t;
    int n = cnt[d];
    int p0 = cursor[d] - n;
    // P2 part: loop-invariant per node
    uint32_t p2u = *(const uint32_t*)(P12 + (size_t)d * 256 + 128 + c0);
    float pv0 = __uint_as_float(p2u << 16);
    float pv1 = __uint_as_float(p2u & 0xFFFF0000u);
    float run0 = 0.f, run1 = 0.f;

    for (int i = 0; i < n; ++i) {
      int p = p0 + i;
      int src = src_s[p];
      int eid = eid_s[p];
      uint32_t p1u = *(const uint32_t*)(P12 + (size_t)src * 256 + c0);
      float h0 = b1v.x + pv0 + __uint_as_float(p1u << 16);
      float h1 = b1v.y + pv1 + __uint_as_float(p1u & 0xFFFF0000u);
      // ea-term: 32-length dot via v_dot2_f32_f16 (f32 accumulate)
      const float* er = ea + (size_t)eid * 32;
      #pragma unroll
      for (int j = 0; j < 16; ++j) {
        float2 e2 = *(const float2*)(er + 2 * j);
        h2 a = __builtin_bit_cast(h2, __builtin_amdgcn_cvt_pkrtz(e2.x, e2.y));
        h0 = __builtin_amdgcn_fdot2(a, __builtin_bit_cast(h2, w[j].x), h0, false);
        h1 = __builtin_amdgcn_fdot2(a, __builtin_bit_cast(h2, w[j].y), h1, false);
      }
      // LayerNorm over 128 cols (full-wave reduce)
      float s = h0 + h1, ss = h0 * h0 + h1 * h1;
      #pragma unroll
      for (int m = 1; m <= 32; m <<= 1) {
        s += __shfl_xor(s, m);
        ss += __shfl_xor(ss, m);
      }
      float mu = s * (1.f / 128.f);
      float rstd = rsqrtf(ss * (1.f / 128.f) - mu * mu + LN_EPS);
      float u0 = (h0 - mu) * rstd * gv.x + bev.x;
      float u1 = (h1 - mu) * rstd * gv.y + bev.y;
      u0 = u0 / (1.f + __expf(-u0));
      u1 = u1 / (1.f + __expf(-u1));
      run0 += u0; run1 += u1;
    }
    float2 o; o.x = run0; o.y = run1;
    *(float2*)(S + (size_t)d * 128 + c0) = o;   // plain store, no atomic
  }
}

// ---------------- T = S @ W2  (N x 128, f32) ----------------

__global__ __launch_bounds__(256) void t_kernel(
    const float* __restrict__ S, const uint16_t* __restrict__ W2p,
    float* __restrict__ T) {
  __shared__ __align__(16) uint16_t A[64 * PH];
  const int tid = threadIdx.x;
  const int n0 = blockIdx.x * 64;

  #pragma unroll
  for (int it = 0; it < 8; ++it) {
    int u = tid + it * 256;
    int r = u >> 5, q = u & 31;
    int node = min(n0 + r, N_NODES - 1);
    float4 f = *(const float4*)(S + (size_t)node * 128 + q * 4);
    ushort4 o;
    o.x = f2bf(f.x); o.y = f2bf(f.y); o.z = f2bf(f.z); o.w = f2bf(f.w);
    *(ushort4*)(&A[r * PH + q * 4]) = o;
  }
  __syncthreads();

  const int wid = tid >> 6, lane = tid & 63;
  const int lrow = lane & 15, lk = lane >> 4;
  const int r0 = wid * 16;

  f32x4 acc[8] = {};
  const uint16_t* Abase = &A[(r0 + lrow) * PH + lk * 8];
  #pragma unroll
  for (int c = 0; c < 4; ++c) {
    short8 a = *(const short8*)(Abase + c * 32);
    #pragma unroll
    for (int n = 0; n < 8; ++n) {
      short8 b = *(const short8*)(W2p + ((size_t)(c * 128 + n * 16 + lrow) * 4 + lk) * 8);
      acc[n] = __builtin_amdgcn_mfma_f32_16x16x32_bf16(a, b, acc[n], 0, 0, 0);
    }
  }

  #pragma unroll
  for (int reg = 0; reg < 4; ++reg) {
    int row = n0 + r0 + lk * 4 + reg;
    if (row < N_NODES) {
      #pragma unroll
      for (int n = 0; n < 8; ++n) {
        T[(size_t)row * 128 + n * 16 + lrow] = acc[n][reg];
      }
    }
  }
}

// ---------------- update kernel: out = x + MLP([x, T + cnt*b2]) ----------------

__global__ __launch_bounds__(256) void upd_kernel(
    const float* __restrict__ x, const float* __restrict__ T,
    const int* __restrict__ cnt, const float* __restrict__ b2m,
    const uint16_t* __restrict__ Wu1p, const float* __restrict__ b1,
    const float* __restrict__ g1, const float* __restrict__ be1,
    const uint16_t* __restrict__ Wu2p, const float* __restrict__ b2,
    float* __restrict__ out) {
  __shared__ __align__(16) uint16_t A[64 * PU];
  __shared__ float sb1[128], sg[128], sbe[128], sb2[64];

  const int tid = threadIdx.x;
  const int n0 = blockIdx.x * 64;

  if (tid < 128) { sb1[tid] = b1[tid]; sg[tid] = g1[tid]; }
  else { sbe[tid - 128] = be1[tid - 128]; if (tid < 192) sb2[tid - 128] = b2[tid - 128]; }

  // stage x (f32 -> bf16)
  #pragma unroll
  for (int it = 0; it < 4; ++it) {
    int u = tid + it * 256;
    int r = u >> 4, q = u & 15;
    int node = min(n0 + r, N_NODES - 1);
    float4 f = *(const float4*)(x + (size_t)node * 64 + q * 4);
    ushort4 o;
    o.x = f2bf(f.x); o.y = f2bf(f.y); o.z = f2bf(f.z); o.w = f2bf(f.w);
    *(ushort4*)(&A[r * PU + q * 4]) = o;
  }
  // stage agg = T + cnt*b2m (f32 -> bf16)
  #pragma unroll
  for (int it = 0; it < 8; ++it) {
    int u = tid + it * 256;
    int r = u >> 5, q = u & 31;
    int node = min(n0 + r, N_NODES - 1);
    float c = (float)cnt[node];
    float4 f = *(const float4*)(T + (size_t)node * 128 + q * 4);
    float4 bb = *(const float4*)(b2m + q * 4);
    ushort4 o;
    o.x = f2bf(f.x + c * bb.x); o.y = f2bf(f.y + c * bb.y);
    o.z = f2bf(f.z + c * bb.z); o.w = f2bf(f.w + c * bb.w);
    *(ushort4*)(&A[r * PU + 64 + q * 4]) = o;
  }
  __syncthreads();

  const int wid = tid >> 6, lane = tid & 63;
  const int lrow = lane & 15, lk = lane >> 4;
  const int r0 = wid * 16;

  // GEMM1: (64x192) @ (192x128)
  f32x4 acc[8] = {};
  const uint16_t* Abase = &A[(r0 + lrow) * PU + lk * 8];
  #pragma unroll
  for (int c = 0; c < 6; ++c) {
    short8 a = *(const short8*)(Abase + c * 32);
    #pragma unroll
    for (int n = 0; n < 8; ++n) {
      short8 b = *(const short8*)(Wu1p + ((size_t)((c * 128) + (n * 16 + lrow)) * 4 + lk) * 8);
      acc[n] = __builtin_amdgcn_mfma_f32_16x16x32_bf16(a, b, acc[n], 0, 0, 0);
    }
  }

  // bias + LN + SiLU -> Hs (strip overlay on A)
  uint16_t* strip = &A[r0 * PU];
  #pragma unroll
  for (int reg = 0; reg < 4; ++reg) {
    float v[8];
    float s = 0.f, ss = 0.f;
    #pragma unroll
    for (int n = 0; n < 8; ++n) {
      v[n] = acc[n][reg] + sb1[n * 16 + lrow];
      s += v[n]; ss += v[n] * v[n];
    }
    #pragma unroll
    for (int m = 1; m <= 8; m <<= 1) {
      s += __shfl_xor(s, m);
      ss += __shfl_xor(ss, m);
    }
    float mu = s * (1.f / 128.f);
    float rstd = rsqrtf(ss * (1.f / 128.f) - mu * mu + LN_EPS);
    uint16_t* hrow = strip + (lk * 4 + reg) * PH;
    #pragma unroll
    for (int n = 0; n < 8; ++n) {
      int col = n * 16 + lrow;
      float h = (v[n] - mu) * rstd * sg[col] + sbe[col];
      h = h / (1.f + __expf(-h));
      hrow[col] = f2bf(h);
    }
  }

  // GEMM2: (64x128) @ (128x64)
  f32x4 acc2[4] = {};
  const uint16_t* Hbase = strip + lrow * PH + lk * 8;
  #pragma unroll
  for (int c = 0; c < 4; ++c) {
    short8 a = *(const short8*)(Hbase + c * 32);
    #pragma unroll
    for (int n = 0; n < 4; ++n) {
      short8 b = *(const short8*)(Wu2p + ((size_t)((c * 64) + (n * 16 + lrow)) * 4 + lk) * 8);
      acc2[n] = __builtin_amdgcn_mfma_f32_16x16x32_bf16(a, b, acc2[n], 0, 0, 0);
    }
  }

  // residual + bias + store f32
  #pragma unroll
  for (int reg = 0; reg < 4; ++reg) {
    int node = n0 + r0 + lk * 4 + reg;
    if (node < N_NODES) {
      #pragma unroll
      for (int n = 0; n < 4; ++n) {
        int col = n * 16 + lrow;
        out[(size_t)node * 64 + col] =
            x[(size_t)node * 64 + col] + acc2[n][reg] + sb2[col];
      }
    }
  }
}

extern "C" void kernel_launch(void* const* d_in, const int* in_sizes, int n_in,
                              void* d_out, int out_size, void* d_ws, size_t ws_size,
                              hipStream_t stream) {
  const float* x   = (const float*)d_in[0];
  const int*   ei  = (const int*)d_in[1];
  const float* ea  = (const float*)d_in[2];
  const float* W1  = (const float*)d_in[3];
  const float* b1  = (const float*)d_in[4];
  const float* g1  = (const float*)d_in[5];
  const float* be1 = (const float*)d_in[6];
  const float* W2  = (const float*)d_in[7];
  const float* b2  = (const float*)d_in[8];
  const float* Wu1 = (const float*)d_in[9];
  const float* bu1 = (const float*)d_in[10];
  const float* gu  = (const float*)d_in[11];
  const float* beu = (const float*)d_in[12];
  const float* Wu2 = (const float*)d_in[13];
  const float* bu2 = (const float*)d_in[14];
  float* out = (float*)d_out;

  char* ws = (char*)d_ws;
  float*    S      = (float*)ws;                       // 51,200,000 (N*128*4)
  uint16_t* P12    = (uint16_t*)(ws + 51200000);       // 51,200,000 (N*256*2)
  float*    T      = (float*)(ws + 51200000);          // aliases P12 (dead by then)
  uint16_t* Wcatp  = (uint16_t*)(ws + 102400000);      // 32,768
  uint16_t* W2p    = (uint16_t*)(ws + 102432768);      // 32,768
  uint16_t* Wu1p   = (uint16_t*)(ws + 102465536);      // 49,152
  uint16_t* Wu2p   = (uint16_t*)(ws + 102514688);      // 16,384
  uint32_t* W1cpk  = (uint32_t*)(ws + 102531072);      // 8,192
  int*      cnt    = (int*)(ws + 102539264);           // 400,000
  int*      offs   = (int*)(ws + 102939264);           // 400,000
  int*      cursor = (int*)(ws + 103339264);           // 400,000
  int*      bsum   = (int*)(ws + 103739264);           // 512
  int*      src_s  = (int*)(ws + 103739776);           // 3,200,000
  int*      eid_s  = (int*)(ws + 106939776);           // 3,200,000 (end ~110.1 MB)

  (void)hipMemsetAsync(cnt, 0, (size_t)N_NODES * 4, stream);

  prep_kernel<<<PREP_HIST_BLKS + PREP_PACK_BLKS, 256, 0, stream>>>(
      ei, cnt, W1, Wcatp, W1cpk, W2, W2p, Wu1, Wu1p, Wu2, Wu2p);

  scan_blk<<<NB_SCAN, 256, 0, stream>>>(cnt, offs, bsum);
  scan_top<<<1, 128, 0, stream>>>(bsum);
  scan_add<<<(N_NODES + 255) / 256, 256, 0, stream>>>(offs, bsum, cursor);
  scatter_edges<<<(N_EDGES + 255) / 256, 256, 0, stream>>>(ei, cursor, src_s, eid_s);

  p12_kernel<<<(N_NODES + 63) / 64, 256, 0, stream>>>(x, Wcatp, P12);

  edge_kernel<<<N_NODES / 8, 256, 0, stream>>>(src_s, eid_s, cursor, cnt, ea, P12,
                                               W1cpk, b1, g1, be1, S);

  t_kernel<<<(N_NODES + 63) / 64, 256, 0, stream>>>(S, W2p, T);

  upd_kernel<<<(N_NODES + 63) / 64, 256, 0, stream>>>(x, T, cnt, b2,
                                                      Wu1p, bu1, gu, beu, Wu2p, bu2, out);
}